// Round 6
// baseline (255.869 us; speedup 1.0000x reference)
//
#include <hip/hip_runtime.h>

// 16 lanes per lane-group, 1 hidden unit per lane (10 real + const + 5 dummy).
// Each lane-group runs TWO batch elements (A,B) with interleaved instruction
// streams -> chain B fills chain A's dependency stalls (1 wave/SIMD, 1024 waves).
// Fast steps advance r = 1/(1+2^a) by 2nd-order Taylor (no transcendentals);
// exact exp2+rcp resync every RS steps bounds drift.
#define CH 16   // steps per prefetch chunk
#define RS 4    // resync period (divides CH)

#if __has_builtin(__builtin_amdgcn_exp2f)
  #define EXP2F(x) __builtin_amdgcn_exp2f(x)
#else
  #define EXP2F(x) exp2f(x)
#endif
#if __has_builtin(__builtin_amdgcn_rcpf)
  #define RCPF(x) __builtin_amdgcn_rcpf(x)
#else
  #define RCPF(x) (1.0f/(x))
#endif

template<int CTRL>
__device__ __forceinline__ float dpp_add(float x) {
    int y = __builtin_amdgcn_update_dpp(0, __float_as_int(x), CTRL, 0xF, 0xF, true);
    return x + __int_as_float(y);
}

__global__ __launch_bounds__(256, 1) void ode_scan(
    const float* __restrict__ t,
    const float* __restrict__ Vs,
    const float* __restrict__ Tm,
    const float* __restrict__ C0,
    const float* __restrict__ R0,
    const float* __restrict__ W1,   // (5,10)
    const float* __restrict__ b1,   // (10)
    const float* __restrict__ W2,   // (10,5)
    const float* __restrict__ b2,   // (5)
    float* __restrict__ out,        // (B, N+1, 2)
    int B, int N)
{
    int tid = blockIdx.x * blockDim.x + threadIdx.x;
    int g = tid >> 4;          // lane-group id
    int u = tid & 15;          // hidden-unit index
    int ngrp = (B + 1) >> 1;
    if (g >= ngrp) return;
    int eA = 2*g;
    int eB = 2*g + 1; if (eB >= B) eB = B - 1;   // duplicate last row if B odd

    const float S   = 2.88539008177792681472f;   // 2*log2(e)
    const float LN2 = 0.69314718055994530942f;

    // Per-lane weights for hidden unit u (shared by both chains; cc is per-element).
    float w0s, w3s, w4s, v3, v4, ccA, ccB;
    if (u < 10) {
        w0s = S*W1[u]; w3s = S*W1[30+u]; w4s = S*W1[40+u];
        ccA = S*fmaf(Vs[eA], W1[10+u], fmaf(Tm[eA], W1[20+u], b1[u]));
        ccB = S*fmaf(Vs[eB], W1[10+u], fmaf(Tm[eB], W1[20+u], b1[u]));
        v3  = -2.0f*W2[5*u+3]; v4 = -2.0f*W2[5*u+4];
    } else if (u == 10) {
        // constant unit: a=-60 -> z=2^-60 -> 1+z==1.0f -> r==1.0 exactly;
        // fast advance: s=r*r-r=0 -> r stays exactly 1.
        w0s = 0.f; w3s = 0.f; w4s = 0.f; ccA = -60.f; ccB = -60.f;
        float c3 = b2[3], c4 = b2[4];
        for (int j = 0; j < 10; ++j) { c3 += W2[5*j+3]; c4 += W2[5*j+4]; }
        v3 = c3; v4 = c4;
    } else {
        w0s = 0.f; w3s = 0.f; w4s = 0.f; ccA = -60.f; ccB = -60.f; v3 = 0.f; v4 = 0.f;
    }

    float CapA = C0[eA], ResA = R0[eA];
    float CapB = C0[eB], ResB = R0[eB];
    const float* trowA = t + (size_t)eA * (N + 1);
    const float* trowB = t + (size_t)eB * (N + 1);
    float* orowA = out + (size_t)eA * (size_t)(N + 1) * 2;
    float* orowB = out + (size_t)eB * (size_t)(N + 1) * 2;
    *(float2*)orowA = make_float2(CapA, ResA);
    *(float2*)orowB = make_float2(CapB, ResB);
    float tpA = trowA[0], tpB = trowB[0];
    float rA = 1.0f, rB = 1.0f;   // valid after first (slow) step

    // One fused pair-step; slow/advance are compile-time under full unroll.
    auto pair_step = [&](float tnA, float tnB, float2& dstA, float2& dstB,
                         bool slow, bool advance) {
        float hA = tnA - tpA;
        float hB = tnB - tpB;
        if (slow) {
            float aA = fmaf(ResA, w4s, fmaf(CapA, w3s, fmaf(tpA, w0s, ccA)));
            float aB = fmaf(ResB, w4s, fmaf(CapB, w3s, fmaf(tpB, w0s, ccB)));
            float zA = EXP2F(aA);
            float zB = EXP2F(aB);
            rA = RCPF(zA + 1.0f);
            rB = RCPF(zB + 1.0f);
        }
        float q3A = rA * v3, q4A = rA * v4;
        float q3B = rB * v3, q4B = rB * v4;
        // 4-stage butterflies over aligned 16-lane groups, interleaved
        q3A = dpp_add<0xB1>(q3A);  q4A = dpp_add<0xB1>(q4A);
        q3B = dpp_add<0xB1>(q3B);  q4B = dpp_add<0xB1>(q4B);
        q3A = dpp_add<0x4E>(q3A);  q4A = dpp_add<0x4E>(q4A);
        q3B = dpp_add<0x4E>(q3B);  q4B = dpp_add<0x4E>(q4B);
        q3A = dpp_add<0x141>(q3A); q4A = dpp_add<0x141>(q4A);
        q3B = dpp_add<0x141>(q3B); q4B = dpp_add<0x141>(q4B);
        q3A = dpp_add<0x140>(q3A); q4A = dpp_add<0x140>(q4A);
        q3B = dpp_add<0x140>(q3B); q4B = dpp_add<0x140>(q4B);
        CapA = fmaf(hA, q3A, CapA);  ResA = fmaf(hA, q4A, ResA);
        CapB = fmaf(hB, q3B, CapB);  ResB = fmaf(hB, q4B, ResB);
        dstA = make_float2(CapA, ResA);
        dstB = make_float2(CapB, ResB);
        if (advance) {
            // r += dl*s * (1 + dl*(r-1/2)),  dl = ln2 * (a_{i+1}-a_i), s = r^2-r
            float sA = fmaf(rA, rA, -rA), sB = fmaf(rB, rB, -rB);
            float rmA = rA - 0.5f,        rmB = rB - 0.5f;
            float hlA = hA * LN2,         hlB = hB * LN2;
            float GA = fmaf(q3A, w3s, fmaf(q4A, w4s, w0s));
            float GB = fmaf(q3B, w3s, fmaf(q4B, w4s, w0s));
            float dlA = hlA * GA,         dlB = hlB * GB;
            float fA = fmaf(dlA, rmA, 1.0f);
            float fB = fmaf(dlB, rmB, 1.0f);
            rA = fmaf(dlA * sA, fA, rA);
            rB = fmaf(dlB * sB, fB, rB);
        }
        tpA = tnA; tpB = tnB;
    };

    int i = 1;
    if (N >= 2*CH) {
        float bA0[CH], bA1[CH], bB0[CH], bB1[CH];
        int nch = N / CH;
        int npair = nch / 2;
        int lim = N + 1 - CH;

#pragma unroll
        for (int m = 0; m < CH; ++m) { bA0[m] = trowA[1+m]; bB0[m] = trowB[1+m]; }

        float2* opA = (float2*)orowA + 1;
        float2* opB = (float2*)orowB + 1;
        for (int p = 0; p < npair; ++p) {
            int c = 2*p;
            {   // process chunk c (buf0), prefetch chunk c+1 into buf1
                int base = (c + 1)*CH + 1; if (base > lim) base = lim;
                const float* lA = trowA + base;
                const float* lB = trowB + base;
#pragma unroll
                for (int m = 0; m < CH; ++m) {
                    bA1[m] = lA[m]; bB1[m] = lB[m];
                    pair_step(bA0[m], bB0[m], opA[m], opB[m],
                              (m % RS) == 0, ((m + 1) % RS) != 0);
                }
                opA += CH; opB += CH;
            }
            {   // process chunk c+1 (buf1), prefetch chunk c+2 into buf0
                int base = (c + 2)*CH + 1; if (base > lim) base = lim;
                const float* lA = trowA + base;
                const float* lB = trowB + base;
#pragma unroll
                for (int m = 0; m < CH; ++m) {
                    bA0[m] = lA[m]; bB0[m] = lB[m];
                    pair_step(bA1[m], bB1[m], opA[m], opB[m],
                              (m % RS) == 0, ((m + 1) % RS) != 0);
                }
                opA += CH; opB += CH;
            }
        }
        i = 2*CH*npair + 1;
    }
    // scalar tail (not hit for N=2048): exact steps only
    for (; i <= N; ++i) {
        pair_step(trowA[i], trowB[i],
                  *(float2*)(orowA + 2*(size_t)i),
                  *(float2*)(orowB + 2*(size_t)i),
                  true, false);
    }
}

extern "C" void kernel_launch(void* const* d_in, const int* in_sizes, int n_in,
                              void* d_out, int out_size, void* d_ws, size_t ws_size,
                              hipStream_t stream) {
    const float* t  = (const float*)d_in[0];
    const float* Vs = (const float*)d_in[1];
    const float* Tm = (const float*)d_in[2];
    const float* C0 = (const float*)d_in[3];
    const float* R0 = (const float*)d_in[4];
    const float* W1 = (const float*)d_in[5];
    const float* b1 = (const float*)d_in[6];
    const float* W2 = (const float*)d_in[7];
    const float* b2 = (const float*)d_in[8];
    float* out = (float*)d_out;

    int B = in_sizes[1];
    int N = in_sizes[0] / B - 1;

    int ngrp = (B + 1) / 2;
    int threads = ngrp * 16;
    dim3 block(256);
    dim3 grid((threads + 255) / 256);
    hipLaunchKernelGGL(ode_scan, grid, block, 0, stream,
                       t, Vs, Tm, C0, R0, W1, b1, W2, b2, out, B, N);
}

// Round 7
// 147.554 us; speedup vs baseline: 1.7341x; 1.7341x over previous
//
#include <hip/hip_runtime.h>

// 8 lanes per batch element; 2 hidden units per lane packed as float2 (VOP3P).
// Steady-state steps advance r = 1/(1+2^a) by a direct 2nd-order Taylor in a
// (no transcendentals, short chain); exact exp2+rcp resync every RS steps.
#define LPE 8
#define CH 16   // steps per prefetch chunk
#define RS 4    // resync period (must divide CH)

typedef float v2f __attribute__((ext_vector_type(2)));

#if __has_builtin(__builtin_amdgcn_exp2f)
  #define EXP2F(x) __builtin_amdgcn_exp2f(x)
#else
  #define EXP2F(x) exp2f(x)
#endif
#if __has_builtin(__builtin_amdgcn_rcpf)
  #define RCPF(x) __builtin_amdgcn_rcpf(x)
#else
  #define RCPF(x) (1.0f/(x))
#endif

template<int CTRL>
__device__ __forceinline__ float dpp_add(float x) {
    int y = __builtin_amdgcn_update_dpp(0, __float_as_int(x), CTRL, 0xF, 0xF, true);
    return x + __int_as_float(y);
}

__device__ __forceinline__ v2f vfma(v2f a, v2f b, v2f c) {
#if __has_builtin(__builtin_elementwise_fma)
    return __builtin_elementwise_fma(a, b, c);
#else
    v2f r; r.x = fmaf(a.x, b.x, c.x); r.y = fmaf(a.y, b.y, c.y); return r;
#endif
}
__device__ __forceinline__ v2f splat(float x) { v2f v; v.x = x; v.y = x; return v; }

__global__ __launch_bounds__(256, 1) void ode_scan(
    const float* __restrict__ t,
    const float* __restrict__ Vs,
    const float* __restrict__ Tm,
    const float* __restrict__ C0,
    const float* __restrict__ R0,
    const float* __restrict__ W1,   // (5,10)
    const float* __restrict__ b1,   // (10)
    const float* __restrict__ W2,   // (10,5)
    const float* __restrict__ b2,   // (5)
    float* __restrict__ out,        // (B, N+1, 2)
    int B, int N)
{
    int tid = blockIdx.x * blockDim.x + threadIdx.x;
    int e = tid >> 3;
    int u = tid & 7;
    if (e >= B) return;

    const float S   = 2.88539008177792681472f;   // 2*log2(e)
    const float LN2 = 0.69314718055994530942f;
    float Vv = Vs[e], Tv = Tm[e];

    // Packed per-lane weights for hidden units j0=2u (x), j1=2u+1 (y).
    v2f W0p, W3p, W4p, CCp, V3p, V4p;
    {
        int j0 = 2*u, j1 = 2*u + 1;
        if (j0 < 10) {
            W0p.x = S*W1[j0]; W3p.x = S*W1[30+j0]; W4p.x = S*W1[40+j0];
            CCp.x = S*fmaf(Vv, W1[10+j0], fmaf(Tv, W1[20+j0], b1[j0]));
            V3p.x = -2.0f*W2[5*j0+3]; V4p.x = -2.0f*W2[5*j0+4];
        } else { W0p.x=0.f; W3p.x=0.f; W4p.x=0.f; CCp.x=-60.f; V3p.x=0.f; V4p.x=0.f; }
        if (j1 < 10) {
            W0p.y = S*W1[j1]; W3p.y = S*W1[30+j1]; W4p.y = S*W1[40+j1];
            CCp.y = S*fmaf(Vv, W1[10+j1], fmaf(Tv, W1[20+j1], b1[j1]));
            V3p.y = -2.0f*W2[5*j1+3]; V4p.y = -2.0f*W2[5*j1+4];
        } else { W0p.y=0.f; W3p.y=0.f; W4p.y=0.f; CCp.y=-60.f; V3p.y=0.f; V4p.y=0.f; }
        if (j0 == 10) {
            // constant unit: a=-60 -> z=2^-60 -> 1+z==1.0f -> r==1.0 exactly;
            // fast advance: s = r*r - r = 0 -> r stays exactly 1.
            float c3 = b2[3], c4 = b2[4];
            for (int j = 0; j < 10; ++j) { c3 += W2[5*j+3]; c4 += W2[5*j+4]; }
            V3p.x = c3; V4p.x = c4;
        }
    }

    const v2f ONEv = splat(1.0f);
    // ln2-scaled weights for the r-advance (dl = ln2 * delta_a)
    v2f W0a = splat(LN2) * W0p;
    v2f W3a = splat(LN2) * W3p;
    v2f W4a = splat(LN2) * W4p;

    float Cap = C0[e], Res = R0[e];
    const float* trow = t + (size_t)e * (N + 1);
    float* orow = out + (size_t)e * (size_t)(N + 1) * 2;
    *(float2*)orow = make_float2(Cap, Res);
    float tprev = trow[0];

    v2f r = ONEv;   // valid after first (slow) step

    // products + 8-lane reduce + state update + store (shared tail)
    auto tail = [&](float h, float tn, float2& dst, float& p3o, float& p4o) {
        v2f q3 = r * V3p;
        v2f q4 = r * V4p;
        float p3 = q3.x + q3.y;
        float p4 = q4.x + q4.y;
        p3 = dpp_add<0xB1>(p3);  p4 = dpp_add<0xB1>(p4);
        p3 = dpp_add<0x4E>(p3);  p4 = dpp_add<0x4E>(p4);
        p3 = dpp_add<0x141>(p3); p4 = dpp_add<0x141>(p4);
        Cap = fmaf(h, p3, Cap);
        Res = fmaf(h, p4, Res);
        tprev = tn;
        dst = make_float2(Cap, Res);
        p3o = p3; p4o = p4;
    };

    // exact step: recompute r from scratch (ground truth, kills drift)
    auto slow_step = [&](float tn, float2& dst) {
        v2f TP = vfma(splat(tprev), W0p, CCp);
        v2f A  = vfma(splat(Res), W4p, vfma(splat(Cap), W3p, TP));
        v2f zz; zz.x = EXP2F(A.x); zz.y = EXP2F(A.y);
        v2f d = zz + ONEv;
        v2f rr; rr.x = RCPF(d.x); rr.y = RCPF(d.y);
        r = rr;
        float h = tn - tprev;
        float p3, p4;
        tail(h, tn, dst, p3, p4);
    };

    // incremental step: 2nd-order Taylor advance of r in a-space.
    // s = r^2 - r and rm = r - 1/2 are off the reduce chain.
    auto fast_step = [&](float tn, float2& dst) {
        float h = tn - tprev;
        v2f s  = vfma(r, r, -r);
        v2f rm = r + splat(-0.5f);
        float p3, p4;
        tail(h, tn, dst, p3, p4);
        v2f G  = vfma(splat(p3), W3a, vfma(splat(p4), W4a, W0a));
        v2f dl = splat(h) * G;
        v2f f  = vfma(dl, rm, ONEv);
        v2f ds = dl * s;
        r = vfma(ds, f, r);
    };

    int i = 1;
    if (N >= 2*CH) {
        float rawA[CH], rawB[CH];
        int nch = N / CH;
        int npair = nch / 2;
        int lim = N + 1 - CH;

#pragma unroll
        for (int m = 0; m < CH; ++m) rawA[m] = trow[1 + m];   // chunk 0

        float2* op = (float2*)orow + 1;
        for (int p = 0; p < npair; ++p) {
            int c = 2*p;
            {   // process chunk c (rawA), prefetch chunk c+1 into rawB
                int base = (c + 1)*CH + 1; if (base > lim) base = lim;
                const float* lp = trow + base;
#pragma unroll
                for (int m = 0; m < CH; ++m) {
                    rawB[m] = lp[m];
                    if ((m % RS) == 0) slow_step(rawA[m], op[m]);
                    else               fast_step(rawA[m], op[m]);
                }
                op += CH;
            }
            {   // process chunk c+1 (rawB), prefetch chunk c+2 into rawA
                int base = (c + 2)*CH + 1; if (base > lim) base = lim;
                const float* lp = trow + base;
#pragma unroll
                for (int m = 0; m < CH; ++m) {
                    rawA[m] = lp[m];
                    if ((m % RS) == 0) slow_step(rawB[m], op[m]);
                    else               fast_step(rawB[m], op[m]);
                }
                op += CH;
            }
        }
        i = 2*CH*npair + 1;
    }
    // scalar tail (not hit for N=2048): all exact steps
    for (; i <= N; ++i) {
        slow_step(trow[i], *(float2*)(orow + 2*(size_t)i));
    }
}

extern "C" void kernel_launch(void* const* d_in, const int* in_sizes, int n_in,
                              void* d_out, int out_size, void* d_ws, size_t ws_size,
                              hipStream_t stream) {
    const float* t  = (const float*)d_in[0];
    const float* Vs = (const float*)d_in[1];
    const float* Tm = (const float*)d_in[2];
    const float* C0 = (const float*)d_in[3];
    const float* R0 = (const float*)d_in[4];
    const float* W1 = (const float*)d_in[5];
    const float* b1 = (const float*)d_in[6];
    const float* W2 = (const float*)d_in[7];
    const float* b2 = (const float*)d_in[8];
    float* out = (float*)d_out;

    int B = in_sizes[1];
    int N = in_sizes[0] / B - 1;

    int threads = B * LPE;
    dim3 block(256);
    dim3 grid((threads + 255) / 256);
    hipLaunchKernelGGL(ode_scan, grid, block, 0, stream,
                       t, Vs, Tm, C0, R0, W1, b1, W2, b2, out, B, N);
}